// Round 14
// baseline (712.342 us; speedup 1.0000x reference)
//
#include <hip/hip_runtime.h>
#include <math.h>

#define N_NODES 50000
#define N_EDGES 800000
#define D 64
#define N_GRAPHS 512
#define N_CLASSES 10
#define NT 3125        // 16-row tiles
#define NB32 1563      // 32-node units (1563*32 >= 50000)
#define NPART 6250     // nodes per XCD partition (50000/8)
#define MEGA_GRID 1024 // 4 blocks/CU * 256 CUs — all resident by construction

#define SCAN_B 512
#define NB_SCAN ((N_NODES + SCAN_B - 1) / SCAN_B)  // 98

typedef __attribute__((ext_vector_type(8))) short bf16x8;
typedef __attribute__((ext_vector_type(4))) float f32x4;

#define MFMA16(a, b, c) __builtin_amdgcn_mfma_f32_16x16x32_bf16(a, b, c, 0, 0, 0)

// ---------------- helpers ----------------

__device__ __forceinline__ unsigned mapf(float f) {
  unsigned u = __float_as_uint(f);
  return (u & 0x80000000u) ? ~u : (u | 0x80000000u);
}
__device__ __forceinline__ float unmapf(unsigned u) {
  return __uint_as_float((u & 0x80000000u) ? (u & 0x7FFFFFFFu) : ~u);
}
__device__ __forceinline__ ushort bf16_rne(float f) {
  unsigned u = __float_as_uint(f);
  u += 0x7FFFu + ((u >> 16) & 1u);
  return (ushort)(u >> 16);
}
__device__ __forceinline__ float bf16_tof(ushort h) {
  return __uint_as_float(((unsigned)h) << 16);
}
__device__ __forceinline__ unsigned pack2(float a, float b) {
  return (unsigned)bf16_rne(a) | ((unsigned)bf16_rne(b) << 16);
}
__device__ __forceinline__ float2 unpack2(unsigned v) {
  return make_float2(__uint_as_float(v << 16), __uint_as_float(v & 0xFFFF0000u));
}

// ---------------- weight fragment prep (hi/lo split) ----------------
// wf (ushorts): per layer 16384: W1hi@0, W1lo@4096, W2hi@8192, W2lo@12288.
// within region: frag f (8), lane (64), v (8): off = f*512 + lane*8 + v
// value = W[k][n], k = (f&1)*32 + (lane>>4)*8 + v, n = (f>>1)*16 + (lane&15)

__global__ void wprep(const float* __restrict__ convW1, const float* __restrict__ convW2,
                      ushort* __restrict__ wf) {
  const int wi = blockIdx.x;  // 0..5 = layer*2 + which
  const int layer = wi >> 1, which = wi & 1;
  const float* W = (which ? convW2 : convW1) + layer * 4096;
  const int t = threadIdx.x;  // 0..511
  const int f = t >> 6, lane = t & 63;
  const int ct = f >> 1, ks = f & 1;
  const int n = ct * 16 + (lane & 15);
  const int k0 = ks * 32 + ((lane >> 4) << 3);
  ushort hi[8], lo[8];
#pragma unroll
  for (int v = 0; v < 8; ++v) {
    float w = W[(k0 + v) * 64 + n];
    ushort h = bf16_rne(w);
    hi[v] = h;
    lo[v] = bf16_rne(w - bf16_tof(h));
  }
  ushort* base = wf + layer * 16384 + which * 8192;
  *(uint4*)(base + f * 512 + lane * 8) = *(uint4*)hi;
  *(uint4*)(base + 4096 + f * 512 + lane * 8) = *(uint4*)lo;
}

// ---------------- CSR build (XCD-partitioned writes) ----------------

__global__ void hist_part(const int* __restrict__ dst, int* __restrict__ deg) {
  const int p = blockIdx.x & 7;
  const int lo = p * NPART, hi = lo + NPART;
  const int stride = (gridDim.x >> 3) * 256;
  for (int e = (blockIdx.x >> 3) * 256 + threadIdx.x; e < N_EDGES; e += stride) {
    int d = dst[e];
    if (d >= lo && d < hi) atomicAdd(&deg[d], 1);
  }
}

__global__ void scan_blocks(const int* __restrict__ deg, int* __restrict__ bsum) {
  __shared__ int sd[SCAN_B];
  int i = blockIdx.x * SCAN_B + threadIdx.x;
  sd[threadIdx.x] = (i < N_NODES) ? deg[i] : 0;
  __syncthreads();
  for (int off = SCAN_B / 2; off > 0; off >>= 1) {
    if (threadIdx.x < off) sd[threadIdx.x] += sd[threadIdx.x + off];
    __syncthreads();
  }
  if (threadIdx.x == 0) bsum[blockIdx.x] = sd[0];
}

__global__ void scan_mid(int* __restrict__ bsum) {
  __shared__ int s[256];
  int t = threadIdx.x;
  if (t < NB_SCAN) s[t] = bsum[t];
  __syncthreads();
  if (t == 0) {
    int run = 0;
    for (int i = 0; i < NB_SCAN; ++i) { int v = s[i]; s[i] = run; run += v; }
  }
  __syncthreads();
  if (t < NB_SCAN) bsum[t] = s[t];
}

__global__ void scan_final(const int* __restrict__ deg, const int* __restrict__ bsum,
                           int* __restrict__ rs, int* __restrict__ cur) {
  __shared__ int sd[SCAN_B];
  int i = blockIdx.x * SCAN_B + threadIdx.x;
  int v = (i < N_NODES) ? deg[i] : 0;
  sd[threadIdx.x] = v;
  __syncthreads();
  for (int off = 1; off < SCAN_B; off <<= 1) {
    int add = (threadIdx.x >= off) ? sd[threadIdx.x - off] : 0;
    __syncthreads();
    sd[threadIdx.x] += add;
    __syncthreads();
  }
  if (i < N_NODES) {
    int ex = bsum[blockIdx.x] + sd[threadIdx.x] - v;
    rs[i] = ex;
    cur[i] = ex;
  }
  if (i == 0) rs[N_NODES] = N_EDGES;
}

__global__ void fill_part(const int* __restrict__ src, const int* __restrict__ dst,
                          int* __restrict__ cur, int* __restrict__ csr) {
  const int p = blockIdx.x & 7;
  const int lo = p * NPART, hi = lo + NPART;
  const int stride = (gridDim.x >> 3) * 256;
  for (int e = (blockIdx.x >> 3) * 256 + threadIdx.x; e < N_EDGES; e += stride) {
    int d = dst[e];
    if (d >= lo && d < hi) {
      int pos = atomicAdd(&cur[d], 1);
      csr[pos] = src[e];
    }
  }
}

// ---------------- mega-kernel building blocks ----------------

__device__ __forceinline__ void stage_weights(const ushort* __restrict__ wfL,
                                              ushort* Wl, int t) {
  const uint4* s = (const uint4*)wfL;
  uint4* d = (uint4*)Wl;
#pragma unroll
  for (int i = 0; i < 8; ++i) d[t + 256 * i] = s[t + 256 * i];
}

// Device-scope grid barrier. All MEGA_GRID blocks are co-resident by
// construction (LDS 37.4KB -> 4 blocks/CU; VGPR well under budget), so the
// spin cannot deadlock. bar[0]=count, bar[1]=generation. Bounded-spin escape.
__device__ __forceinline__ void grid_barrier(unsigned* bar, int nb, int t) {
  __threadfence();     // release this block's writes (all threads)
  __syncthreads();
  if (t == 0) {
    unsigned g = atomicAdd(&bar[1], 0u);       // current generation
    unsigned old = atomicAdd(&bar[0], 1u);     // arrive
    if (old == (unsigned)nb - 1u) {
      atomicExch(&bar[0], 0u);                 // reset count BEFORE gen flip
      __threadfence();
      atomicAdd(&bar[1], 1u);                  // open next generation
    } else {
      unsigned spins = 0;
      while (atomicAdd(&bar[1], 0u) == g) {
        if (++spins > (1u << 30)) break;       // escape hatch (never expected)
      }
    }
  }
  __syncthreads();
  __threadfence();     // acquire: subsequent reads see other blocks' writes
}

// One 32-node unit (R12-verified): gather (quarter-wave/node, depth 2) ->
// LDS At -> MFMA MLP on waves 0,1.
// A-frag: lane row=lane&15, k=(ks*32)+(lane>>4)*8+v. C/D: col=lane&15, row=(lane>>4)*4+j.
template <int F32IN, int FINAL>
__device__ __forceinline__ void unit_body(
    int unit, const void* __restrict__ hin_, unsigned* __restrict__ hout,
    const int* __restrict__ csr, const int* __restrict__ rs,
    const ushort* Wl, ushort (*At)[72],
    const float* __restrict__ b1, const float* __restrict__ b2,
    const int* __restrict__ batch, unsigned* __restrict__ gU, int t) {
  // ---- gather ----
  {
    const int qw = t >> 4, ql = t & 15;
    const float4* hf = (const float4*)hin_;  // f32 row = 16 float4
    const uint2* hb = (const uint2*)hin_;    // bf16 row = 16 uint2
#pragma unroll
    for (int i = 0; i < 2; ++i) {
      const int nl = qw + 16 * i;
      const int node = unit * 32 + nl;
      float ax = 0.f, ay = 0.f, az = 0.f, aw = 0.f;
      if (node < N_NODES) {
        if (F32IN) {
          float4 v = hf[node * 16 + ql];
          ax = v.x; ay = v.y; az = v.z; aw = v.w;
        } else {
          uint2 u = hb[node * 16 + ql];
          float2 p0 = unpack2(u.x), p1 = unpack2(u.y);
          ax = p0.x; ay = p0.y; az = p1.x; aw = p1.y;
        }
        int e = rs[node];
        const int e1 = rs[node + 1];
        if (F32IN) {
          for (; e + 4 <= e1; e += 4) {
            int s0 = csr[e], s1 = csr[e + 1], s2 = csr[e + 2], s3 = csr[e + 3];
            float4 v0 = hf[s0 * 16 + ql];
            float4 v1 = hf[s1 * 16 + ql];
            float4 v2 = hf[s2 * 16 + ql];
            float4 v3 = hf[s3 * 16 + ql];
            ax += v0.x + v1.x; ay += v0.y + v1.y; az += v0.z + v1.z; aw += v0.w + v1.w;
            ax += v2.x + v3.x; ay += v2.y + v3.y; az += v2.z + v3.z; aw += v2.w + v3.w;
          }
          for (; e < e1; ++e) {
            float4 v = hf[csr[e] * 16 + ql];
            ax += v.x; ay += v.y; az += v.z; aw += v.w;
          }
        } else {
          for (; e + 4 <= e1; e += 4) {
            int s0 = csr[e], s1 = csr[e + 1], s2 = csr[e + 2], s3 = csr[e + 3];
            uint2 u0 = hb[s0 * 16 + ql];
            uint2 u1 = hb[s1 * 16 + ql];
            uint2 u2 = hb[s2 * 16 + ql];
            uint2 u3 = hb[s3 * 16 + ql];
            float2 q0, q1;
            q0 = unpack2(u0.x); q1 = unpack2(u0.y); ax += q0.x; ay += q0.y; az += q1.x; aw += q1.y;
            q0 = unpack2(u1.x); q1 = unpack2(u1.y); ax += q0.x; ay += q0.y; az += q1.x; aw += q1.y;
            q0 = unpack2(u2.x); q1 = unpack2(u2.y); ax += q0.x; ay += q0.y; az += q1.x; aw += q1.y;
            q0 = unpack2(u3.x); q1 = unpack2(u3.y); ax += q0.x; ay += q0.y; az += q1.x; aw += q1.y;
          }
          for (; e < e1; ++e) {
            uint2 u = hb[csr[e] * 16 + ql];
            float2 q0 = unpack2(u.x), q1 = unpack2(u.y);
            ax += q0.x; ay += q0.y; az += q1.x; aw += q1.y;
          }
        }
      }
      *(uint2*)&At[nl][4 * ql] = make_uint2(pack2(ax, ay), pack2(az, aw));
    }
  }
  __syncthreads();  // gather tile ready

  // ---- MLP: waves 0,1 ----
  const int w = t >> 6, lane = t & 63;
  const int tile = unit * 2 + w;
  if (w < 2 && tile < NT) {
    const int m = lane & 15, g = lane >> 4;
    ushort* tw = &At[w * 16][0];
    bf16x8 a0 = *(const bf16x8*)&At[w * 16 + m][g * 8];
    bf16x8 a1 = *(const bf16x8*)&At[w * 16 + m][32 + g * 8];
    const char* wb = (const char*)Wl + lane * 16;
#define LDW(off) (*(const bf16x8*)(wb + (off)))

    f32x4 c0 = {0.f, 0.f, 0.f, 0.f}, c1 = c0, c2 = c0, c3 = c0;
#define G1(ct, cc)                                      \
    cc = MFMA16(a0, LDW((2 * ct + 0) * 1024), cc);      \
    cc = MFMA16(a1, LDW((2 * ct + 1) * 1024), cc);      \
    cc = MFMA16(a0, LDW(8192 + (2 * ct + 0) * 1024), cc); \
    cc = MFMA16(a1, LDW(8192 + (2 * ct + 1) * 1024), cc);
    G1(0, c0) G1(1, c1) G1(2, c2) G1(3, c3)
#undef G1

    {
      float bv0 = b1[m], bv1 = b1[16 + m], bv2 = b1[32 + m], bv3 = b1[48 + m];
#define WRT(cc, ct, bv)                                                    \
      tw[(g * 4 + 0) * 72 + ct * 16 + m] = bf16_rne(fmaxf(cc[0] + bv, 0.f)); \
      tw[(g * 4 + 1) * 72 + ct * 16 + m] = bf16_rne(fmaxf(cc[1] + bv, 0.f)); \
      tw[(g * 4 + 2) * 72 + ct * 16 + m] = bf16_rne(fmaxf(cc[2] + bv, 0.f)); \
      tw[(g * 4 + 3) * 72 + ct * 16 + m] = bf16_rne(fmaxf(cc[3] + bv, 0.f));
      WRT(c0, 0, bv0) WRT(c1, 1, bv1) WRT(c2, 2, bv2) WRT(c3, 3, bv3)
#undef WRT
    }
    bf16x8 h0 = *(const bf16x8*)(tw + m * 72 + g * 8);
    bf16x8 h1 = *(const bf16x8*)(tw + m * 72 + 32 + g * 8);

    c0 = (f32x4){0.f, 0.f, 0.f, 0.f}; c1 = c0; c2 = c0; c3 = c0;
#define G2(ct, cc)                                       \
    cc = MFMA16(h0, LDW(16384 + (2 * ct + 0) * 1024), cc); \
    cc = MFMA16(h1, LDW(16384 + (2 * ct + 1) * 1024), cc); \
    cc = MFMA16(h0, LDW(24576 + (2 * ct + 0) * 1024), cc); \
    cc = MFMA16(h1, LDW(24576 + (2 * ct + 1) * 1024), cc);
    G2(0, c0) G2(1, c1) G2(2, c2) G2(3, c3)
#undef G2
#undef LDW

    const float bv20 = b2[m], bv21 = b2[16 + m], bv22 = b2[32 + m], bv23 = b2[48 + m];
    if (FINAL) {
      const int tb = tile * 16;
#define PM(cc, ct, bv, j)                                           \
      atomicMax(&gU[batch[tb + g * 4 + j] * 64 + ct * 16 + m], mapf(cc[j] + bv));
#define PM4(cc, ct, bv) PM(cc, ct, bv, 0) PM(cc, ct, bv, 1) PM(cc, ct, bv, 2) PM(cc, ct, bv, 3)
      PM4(c0, 0, bv20) PM4(c1, 1, bv21) PM4(c2, 2, bv22) PM4(c3, 3, bv23)
#undef PM4
#undef PM
    } else {
#define WRO(cc, ct, bv)                                        \
      tw[(g * 4 + 0) * 72 + ct * 16 + m] = bf16_rne(cc[0] + bv); \
      tw[(g * 4 + 1) * 72 + ct * 16 + m] = bf16_rne(cc[1] + bv); \
      tw[(g * 4 + 2) * 72 + ct * 16 + m] = bf16_rne(cc[2] + bv); \
      tw[(g * 4 + 3) * 72 + ct * 16 + m] = bf16_rne(cc[3] + bv);
      WRO(c0, 0, bv20) WRO(c1, 1, bv21) WRO(c2, 2, bv22) WRO(c3, 3, bv23)
#undef WRO
      const int r = lane >> 2, q = lane & 3;
      uint4 v0 = *(const uint4*)(tw + r * 72 + q * 16);
      uint4 v1 = *(const uint4*)(tw + r * 72 + q * 16 + 8);
      ushort* Ao = (ushort*)hout + (size_t)tile * 1024;
      *(uint4*)(Ao + lane * 16) = v0;
      *(uint4*)(Ao + lane * 16 + 8) = v1;
    }
  }
  __syncthreads();  // protect At before next unit's gather
}

// ---------------- persistent 3-layer mega-kernel (manual grid barrier) ----------------

__global__ __launch_bounds__(256, 4) void gin_mega(
    const float* __restrict__ x, unsigned* __restrict__ hbA, unsigned* __restrict__ hbB,
    const int* __restrict__ csr, const int* __restrict__ rs,
    const ushort* __restrict__ wf,
    const float* __restrict__ convb1, const float* __restrict__ convb2,
    const int* __restrict__ batch, unsigned* __restrict__ gU,
    unsigned* __restrict__ bar) {
  __shared__ ushort Wl[16384];    // 32KB weight fragments (per-layer staged)
  __shared__ ushort At[32][72];   // 4.5KB gather/transpose tile
  const int t = threadIdx.x;
  const int bid = blockIdx.x;

  // ---- layer 1 (f32 input) ----
  stage_weights(wf, Wl, t);
  __syncthreads();
  for (int u = bid; u < NB32; u += MEGA_GRID)
    unit_body<1, 0>(u, x, hbA, csr, rs, Wl, At, convb1, convb2, batch, gU, t);
  grid_barrier(bar, MEGA_GRID, t);

  // ---- layer 2 ----
  stage_weights(wf + 16384, Wl, t);
  __syncthreads();
  for (int u = bid; u < NB32; u += MEGA_GRID)
    unit_body<0, 0>(u, hbA, hbB, csr, rs, Wl, At, convb1 + 64, convb2 + 64,
                    batch, gU, t);
  grid_barrier(bar + 2, MEGA_GRID, t);

  // ---- layer 3 (final -> pool atomics) ----
  stage_weights(wf + 32768, Wl, t);
  __syncthreads();
  for (int u = bid; u < NB32; u += MEGA_GRID)
    unit_body<0, 1>(u, hbB, nullptr, csr, rs, Wl, At, convb1 + 128, convb2 + 128,
                    batch, gU, t);
}

// ---------------- pooling init + head ----------------

__global__ void init_g(unsigned* __restrict__ gU) {
  int i = blockIdx.x * blockDim.x + threadIdx.x;
  if (i < N_GRAPHS * D) gU[i] = 0x007FFFFFu;  // mapf(-inf)
}

__global__ void head_kernel(const unsigned* __restrict__ gU,
                            const float* __restrict__ fcW1, const float* __restrict__ fcb1,
                            const float* __restrict__ fcW2, const float* __restrict__ fcb2,
                            float* __restrict__ out) {
  __shared__ float gbuf[64];
  __shared__ float hid[64];
  __shared__ float logit[N_CLASSES];
  __shared__ float red[2];
  const int gi = blockIdx.x;
  const int t = threadIdx.x;

  gbuf[t] = unmapf(gU[gi * D + t]);
  __syncthreads();

  float a = fcb1[t];
#pragma unroll
  for (int k = 0; k < 64; ++k) a = fmaf(gbuf[k], fcW1[k * 64 + t], a);
  hid[t] = fmaxf(a, 0.0f);
  __syncthreads();

  if (t < N_CLASSES) {
    float l = fcb2[t];
#pragma unroll
    for (int k = 0; k < 64; ++k) l = fmaf(hid[k], fcW2[k * N_CLASSES + t], l);
    logit[t] = l;
  }
  __syncthreads();

  if (t == 0) {
    float mx = logit[0];
    for (int i = 1; i < N_CLASSES; ++i) mx = fmaxf(mx, logit[i]);
    float s = 0.0f;
    for (int i = 0; i < N_CLASSES; ++i) s += expf(logit[i] - mx);
    red[0] = mx;
    red[1] = logf(s);
  }
  __syncthreads();

  if (t < N_CLASSES) out[gi * N_CLASSES + t] = logit[t] - red[0] - red[1];
}

// ---------------- launch ----------------

extern "C" void kernel_launch(void* const* d_in, const int* in_sizes, int n_in,
                              void* d_out, int out_size, void* d_ws, size_t ws_size,
                              hipStream_t stream) {
  const float* x      = (const float*)d_in[0];
  const float* convW1 = (const float*)d_in[1];
  const float* convb1 = (const float*)d_in[2];
  const float* convW2 = (const float*)d_in[3];
  const float* convb2 = (const float*)d_in[4];
  const float* fcW1   = (const float*)d_in[5];
  const float* fcb1   = (const float*)d_in[6];
  const float* fcW2   = (const float*)d_in[7];
  const float* fcb2   = (const float*)d_in[8];
  const int*   edge   = (const int*)d_in[9];
  const int*   batch  = (const int*)d_in[10];
  float* out = (float*)d_out;

  const int* src = edge;
  const int* dst = edge + N_EDGES;

  // workspace layout (~16.6 MB)
  unsigned* hbA = (unsigned*)d_ws;                  // 6.4 MB bf16 h1
  unsigned* hbB = hbA + (size_t)N_NODES * 32;       // 6.4 MB bf16 h2
  unsigned* gU  = hbB + (size_t)N_NODES * 32;       // 131 KB
  int* rs  = (int*)(gU + N_GRAPHS * D);             // 200 KB
  int* csr = rs + N_NODES + 1;                      // 3.2 MB
  ushort* wf = (ushort*)(csr + N_EDGES);            // 96 KB
  unsigned* bar = (unsigned*)(wf + 49152);          // 16 B barrier state
  // deg/cur/bsum overlap hbA (dead before mega writes hbA)
  int* deg  = (int*)hbA;
  int* cur  = deg + N_NODES;
  int* bsum = cur + N_NODES;

  // ---- prep ----
  wprep<<<6, 512, 0, stream>>>(convW1, convW2, wf);
  init_g<<<(N_GRAPHS * D + 255) / 256, 256, 0, stream>>>(gU);
  hipMemsetAsync(bar, 0, 4 * sizeof(unsigned), stream);

  // ---- CSR build (dst-indexed, XCD-partitioned writes) ----
  hipMemsetAsync(deg, 0, N_NODES * sizeof(int), stream);
  hist_part<<<2048, 256, 0, stream>>>(dst, deg);
  scan_blocks<<<NB_SCAN, SCAN_B, 0, stream>>>(deg, bsum);
  scan_mid<<<1, 256, 0, stream>>>(bsum);
  scan_final<<<NB_SCAN, SCAN_B, 0, stream>>>(deg, bsum, rs, cur);
  fill_part<<<2048, 256, 0, stream>>>(src, dst, cur, csr);

  // ---- 3 fused GIN layers in ONE persistent dispatch (manual barrier) ----
  gin_mega<<<MEGA_GRID, 256, 0, stream>>>(x, hbA, hbB, csr, rs, wf,
                                          convb1, convb2, batch, gU, bar);

  // ---- FC head + log_softmax ----
  head_kernel<<<N_GRAPHS, 64, 0, stream>>>(gU, fcW1, fcb1, fcW2, fcb2, out);
}

// Round 15
// 256.835 us; speedup vs baseline: 2.7735x; 2.7735x over previous
//
#include <hip/hip_runtime.h>
#include <math.h>

#define N_NODES 50000
#define N_EDGES 800000
#define D 64
#define N_GRAPHS 512
#define N_CLASSES 10
#define NTILE 3125     // 16-row tiles
#define NPART 6250     // nodes per XCD partition (50000/8)

#define SCAN_B 512
#define NB_SCAN ((N_NODES + SCAN_B - 1) / SCAN_B)  // 98

typedef __attribute__((ext_vector_type(8))) short bf16x8;
typedef __attribute__((ext_vector_type(4))) float f32x4;
typedef __attribute__((ext_vector_type(2))) unsigned uint2v;
typedef __attribute__((ext_vector_type(4))) unsigned uint4v;

#define MFMA16(a, b, c) __builtin_amdgcn_mfma_f32_16x16x32_bf16(a, b, c, 0, 0, 0)

// ---------------- helpers ----------------

__device__ __forceinline__ unsigned mapf(float f) {
  unsigned u = __float_as_uint(f);
  return (u & 0x80000000u) ? ~u : (u | 0x80000000u);
}
__device__ __forceinline__ float unmapf(unsigned u) {
  return __uint_as_float((u & 0x80000000u) ? (u & 0x7FFFFFFFu) : ~u);
}
__device__ __forceinline__ ushort bf16_rne(float f) {
  unsigned u = __float_as_uint(f);
  u += 0x7FFFu + ((u >> 16) & 1u);
  return (ushort)(u >> 16);
}
__device__ __forceinline__ float bf16_tof(ushort h) {
  return __uint_as_float(((unsigned)h) << 16);
}
__device__ __forceinline__ unsigned pack2(float a, float b) {
  return (unsigned)bf16_rne(a) | ((unsigned)bf16_rne(b) << 16);
}
__device__ __forceinline__ float2 unpack2(unsigned v) {
  return make_float2(__uint_as_float(v << 16), __uint_as_float(v & 0xFFFF0000u));
}

// ---------------- x -> bf16 (non-temporal out) ----------------

__global__ void to_bf16(const float* __restrict__ in, unsigned* __restrict__ out) {
  int i = blockIdx.x * 256 + threadIdx.x;
  float4 v = reinterpret_cast<const float4*>(in)[i];
  uint2v u = {pack2(v.x, v.y), pack2(v.z, v.w)};
  __builtin_nontemporal_store(u, reinterpret_cast<uint2v*>(out) + i);
}

// ---------------- weight fragment prep (hi/lo split) ----------------
// wf (ushorts): per layer 16384: W1hi@0, W1lo@4096, W2hi@8192, W2lo@12288.
// within region: frag f (8), lane (64), v (8): off = f*512 + lane*8 + v
// value = W[k][n], k = (f&1)*32 + (lane>>4)*8 + v, n = (f>>1)*16 + (lane&15)

__global__ void wprep(const float* __restrict__ convW1, const float* __restrict__ convW2,
                      ushort* __restrict__ wf) {
  const int wi = blockIdx.x;  // 0..5 = layer*2 + which
  const int layer = wi >> 1, which = wi & 1;
  const float* W = (which ? convW2 : convW1) + layer * 4096;
  const int t = threadIdx.x;  // 0..511
  const int f = t >> 6, lane = t & 63;
  const int ct = f >> 1, ks = f & 1;
  const int n = ct * 16 + (lane & 15);
  const int k0 = ks * 32 + ((lane >> 4) << 3);
  ushort hi[8], lo[8];
#pragma unroll
  for (int v = 0; v < 8; ++v) {
    float w = W[(k0 + v) * 64 + n];
    ushort h = bf16_rne(w);
    hi[v] = h;
    lo[v] = bf16_rne(w - bf16_tof(h));
  }
  ushort* base = wf + layer * 16384 + which * 8192;
  *(uint4*)(base + f * 512 + lane * 8) = *(uint4*)hi;
  *(uint4*)(base + 4096 + f * 512 + lane * 8) = *(uint4*)lo;
}

// ---------------- CSR build (XCD-partitioned writes) ----------------

__global__ void hist_part(const int* __restrict__ dst, int* __restrict__ deg) {
  const int p = blockIdx.x & 7;
  const int lo = p * NPART, hi = lo + NPART;
  const int stride = (gridDim.x >> 3) * 256;
  for (int e = (blockIdx.x >> 3) * 256 + threadIdx.x; e < N_EDGES; e += stride) {
    int d = dst[e];
    if (d >= lo && d < hi) atomicAdd(&deg[d], 1);
  }
}

__global__ void scan_blocks(const int* __restrict__ deg, int* __restrict__ bsum) {
  __shared__ int sd[SCAN_B];
  int i = blockIdx.x * SCAN_B + threadIdx.x;
  sd[threadIdx.x] = (i < N_NODES) ? deg[i] : 0;
  __syncthreads();
  for (int off = SCAN_B / 2; off > 0; off >>= 1) {
    if (threadIdx.x < off) sd[threadIdx.x] += sd[threadIdx.x + off];
    __syncthreads();
  }
  if (threadIdx.x == 0) bsum[blockIdx.x] = sd[0];
}

__global__ void scan_mid(int* __restrict__ bsum) {
  __shared__ int s[256];
  int t = threadIdx.x;
  if (t < NB_SCAN) s[t] = bsum[t];
  __syncthreads();
  if (t == 0) {
    int run = 0;
    for (int i = 0; i < NB_SCAN; ++i) { int v = s[i]; s[i] = run; run += v; }
  }
  __syncthreads();
  if (t < NB_SCAN) bsum[t] = s[t];
}

__global__ void scan_final(const int* __restrict__ deg, const int* __restrict__ bsum,
                           int* __restrict__ rs, int* __restrict__ cur) {
  __shared__ int sd[SCAN_B];
  int i = blockIdx.x * SCAN_B + threadIdx.x;
  int v = (i < N_NODES) ? deg[i] : 0;
  sd[threadIdx.x] = v;
  __syncthreads();
  for (int off = 1; off < SCAN_B; off <<= 1) {
    int add = (threadIdx.x >= off) ? sd[threadIdx.x - off] : 0;
    __syncthreads();
    sd[threadIdx.x] += add;
    __syncthreads();
  }
  if (i < N_NODES) {
    int ex = bsum[blockIdx.x] + sd[threadIdx.x] - v;
    rs[i] = ex;
    cur[i] = ex;
  }
  if (i == 0) rs[N_NODES] = N_EDGES;
}

__global__ void fill_part(const int* __restrict__ src, const int* __restrict__ dst,
                          int* __restrict__ cur, int* __restrict__ csr) {
  const int p = blockIdx.x & 7;
  const int lo = p * NPART, hi = lo + NPART;
  const int stride = (gridDim.x >> 3) * 256;
  for (int e = (blockIdx.x >> 3) * 256 + threadIdx.x; e < N_EDGES; e += stride) {
    int d = dst[e];
    if (d >= lo && d < hi) {
      int pos = atomicAdd(&cur[d], 1);
      csr[pos] = src[e];
    }
  }
}

// ---------------- GIN aggregation body (NTS: non-temporal store of output) ----------------

template <int NTS>
__device__ __forceinline__ void agg_body(
    const unsigned* __restrict__ hin, const int* __restrict__ csr,
    const int* __restrict__ rs, unsigned* __restrict__ hout, int bid, int t) {
  const int hw = t >> 5, hl = t & 31;
  const int node = bid * 8 + hw;
  float2 a = unpack2(hin[node * 32 + hl]);  // self term
  int e = rs[node];
  const int e1 = rs[node + 1];
  for (; e + 4 <= e1; e += 4) {
    int s0 = csr[e], s1 = csr[e + 1], s2 = csr[e + 2], s3 = csr[e + 3];
    float2 v0 = unpack2(hin[s0 * 32 + hl]);
    float2 v1 = unpack2(hin[s1 * 32 + hl]);
    float2 v2 = unpack2(hin[s2 * 32 + hl]);
    float2 v3 = unpack2(hin[s3 * 32 + hl]);
    a.x += v0.x + v1.x; a.y += v0.y + v1.y;
    a.x += v2.x + v3.x; a.y += v2.y + v3.y;
  }
  for (; e < e1; ++e) {
    float2 v = unpack2(hin[csr[e] * 32 + hl]);
    a.x += v.x; a.y += v.y;
  }
  unsigned val = pack2(a.x, a.y);
  if (NTS) __builtin_nontemporal_store(val, &hout[node * 32 + hl]);
  else     hout[node * 32 + hl] = val;
}

__global__ __launch_bounds__(256) void agg_bf16(
    const unsigned* __restrict__ hin, const int* __restrict__ csr,
    const int* __restrict__ rs, unsigned* __restrict__ hout) {
  agg_body<1>(hin, csr, rs, hout, blockIdx.x, threadIdx.x);
}

// diagnostic: identical gather, REGULAR stores (produces dirty lines)
__global__ __launch_bounds__(256) void abl_again(
    const unsigned* __restrict__ hin, const int* __restrict__ csr,
    const int* __restrict__ rs, unsigned* __restrict__ hout) {
  agg_body<0>(hin, csr, rs, hout, blockIdx.x, threadIdx.x);
}

// ---------------- MFMA MLP body ----------------
// A-frag: lane row=lane&15, k=(ks*32)+(lane>>4)*8+v. C/D: col=lane&15, row=(lane>>4)*4+j.

template <int FINAL, int NTS>
__device__ __forceinline__ void mlp_body(
    const unsigned* __restrict__ Ain, unsigned* __restrict__ Aout,
    const ushort* __restrict__ wfL,
    const float* __restrict__ b1, const float* __restrict__ b2,
    const int* __restrict__ batch, unsigned* __restrict__ gU,
    ushort* Wl, ushort* tb, int bid, int t) {
  const int w = t >> 6, lane = t & 63;
  const int tile = bid * 4 + w;
  const bool act = (tile < NTILE);
  const int m = lane & 15, g = lane >> 4;
  ushort* tw = tb + w * (16 * 72);

  {
    const uint4* s = (const uint4*)wfL;
    uint4* d = (uint4*)Wl;
#pragma unroll
    for (int i = 0; i < 8; ++i) d[t + 256 * i] = s[t + 256 * i];
  }
  bf16x8 a0 = {}, a1 = {};
  if (act) {
    const ushort* Ar = (const ushort*)Ain + (size_t)(tile * 16 + m) * 64;
    a0 = *(const bf16x8*)(Ar + g * 8);
    a1 = *(const bf16x8*)(Ar + 32 + g * 8);
  }
  __syncthreads();

  if (act) {
    const char* wb = (const char*)Wl + lane * 16;
#define LDW(off) (*(const bf16x8*)(wb + (off)))
    f32x4 c0 = {0.f, 0.f, 0.f, 0.f}, c1 = c0, c2 = c0, c3 = c0;
#define G1(ct, cc)                                      \
    cc = MFMA16(a0, LDW((2 * ct + 0) * 1024), cc);      \
    cc = MFMA16(a1, LDW((2 * ct + 1) * 1024), cc);      \
    cc = MFMA16(a0, LDW(8192 + (2 * ct + 0) * 1024), cc); \
    cc = MFMA16(a1, LDW(8192 + (2 * ct + 1) * 1024), cc);
    G1(0, c0) G1(1, c1) G1(2, c2) G1(3, c3)
#undef G1

    {
      float bv0 = b1[m], bv1 = b1[16 + m], bv2 = b1[32 + m], bv3 = b1[48 + m];
#define WRT(cc, ct, bv)                                                    \
      tw[(g * 4 + 0) * 72 + ct * 16 + m] = bf16_rne(fmaxf(cc[0] + bv, 0.f)); \
      tw[(g * 4 + 1) * 72 + ct * 16 + m] = bf16_rne(fmaxf(cc[1] + bv, 0.f)); \
      tw[(g * 4 + 2) * 72 + ct * 16 + m] = bf16_rne(fmaxf(cc[2] + bv, 0.f)); \
      tw[(g * 4 + 3) * 72 + ct * 16 + m] = bf16_rne(fmaxf(cc[3] + bv, 0.f));
      WRT(c0, 0, bv0) WRT(c1, 1, bv1) WRT(c2, 2, bv2) WRT(c3, 3, bv3)
#undef WRT
    }
    bf16x8 h0 = *(const bf16x8*)(tw + m * 72 + g * 8);
    bf16x8 h1 = *(const bf16x8*)(tw + m * 72 + 32 + g * 8);

    c0 = (f32x4){0.f, 0.f, 0.f, 0.f}; c1 = c0; c2 = c0; c3 = c0;
#define G2(ct, cc)                                       \
    cc = MFMA16(h0, LDW(16384 + (2 * ct + 0) * 1024), cc); \
    cc = MFMA16(h1, LDW(16384 + (2 * ct + 1) * 1024), cc); \
    cc = MFMA16(h0, LDW(24576 + (2 * ct + 0) * 1024), cc); \
    cc = MFMA16(h1, LDW(24576 + (2 * ct + 1) * 1024), cc);
    G2(0, c0) G2(1, c1) G2(2, c2) G2(3, c3)
#undef G2
#undef LDW

    const float bv20 = b2[m], bv21 = b2[16 + m], bv22 = b2[32 + m], bv23 = b2[48 + m];
    if (FINAL) {
      int b40 = batch[tile * 16 + g * 4 + 0];
      int b41 = batch[tile * 16 + g * 4 + 1];
      int b42 = batch[tile * 16 + g * 4 + 2];
      int b43 = batch[tile * 16 + g * 4 + 3];
#define PM(cc, ct, bv)                                          \
      atomicMax(&gU[b40 * 64 + ct * 16 + m], mapf(cc[0] + bv)); \
      atomicMax(&gU[b41 * 64 + ct * 16 + m], mapf(cc[1] + bv)); \
      atomicMax(&gU[b42 * 64 + ct * 16 + m], mapf(cc[2] + bv)); \
      atomicMax(&gU[b43 * 64 + ct * 16 + m], mapf(cc[3] + bv));
      PM(c0, 0, bv20) PM(c1, 1, bv21) PM(c2, 2, bv22) PM(c3, 3, bv23)
#undef PM
    } else {
#define WRO(cc, ct, bv)                                        \
      tw[(g * 4 + 0) * 72 + ct * 16 + m] = bf16_rne(cc[0] + bv); \
      tw[(g * 4 + 1) * 72 + ct * 16 + m] = bf16_rne(cc[1] + bv); \
      tw[(g * 4 + 2) * 72 + ct * 16 + m] = bf16_rne(cc[2] + bv); \
      tw[(g * 4 + 3) * 72 + ct * 16 + m] = bf16_rne(cc[3] + bv);
      WRO(c0, 0, bv20) WRO(c1, 1, bv21) WRO(c2, 2, bv22) WRO(c3, 3, bv23)
#undef WRO
      const int r = lane >> 2, q = lane & 3;
      uint4v v0 = *(const uint4v*)(tw + r * 72 + q * 16);
      uint4v v1 = *(const uint4v*)(tw + r * 72 + q * 16 + 8);
      ushort* Ao = (ushort*)Aout + (size_t)tile * 1024;
      if (NTS) {
        __builtin_nontemporal_store(v0, (uint4v*)(Ao + lane * 16));
        __builtin_nontemporal_store(v1, (uint4v*)(Ao + lane * 16 + 8));
      } else {
        *(uint4v*)(Ao + lane * 16) = v0;
        *(uint4v*)(Ao + lane * 16 + 8) = v1;
      }
    }
  }
}

template <int FINAL>
__global__ __launch_bounds__(256, 2) void mlp_bf16(
    const unsigned* __restrict__ Ain, unsigned* __restrict__ Aout,
    const ushort* __restrict__ wfL,
    const float* __restrict__ b1, const float* __restrict__ b2,
    const int* __restrict__ batch, unsigned* __restrict__ gU) {
  __shared__ ushort Wl[16384];
  __shared__ ushort tb[4 * 16 * 72];
  mlp_body<FINAL, 1>(Ain, Aout, wfL, b1, b2, batch, gU, Wl, tb,
                     blockIdx.x, threadIdx.x);
}

// diagnostic: identical MLP, regular stores, reads fresh-dirty input
__global__ __launch_bounds__(256, 2) void abl_fresh(
    const unsigned* __restrict__ Ain, unsigned* __restrict__ Aout,
    const ushort* __restrict__ wfL,
    const float* __restrict__ b1, const float* __restrict__ b2,
    const int* __restrict__ batch, unsigned* __restrict__ gU) {
  __shared__ ushort Wl[16384];
  __shared__ ushort tb[4 * 16 * 72];
  mlp_body<0, 0>(Ain, Aout, wfL, b1, b2, batch, gU, Wl, tb,
                 blockIdx.x, threadIdx.x);
}

// ---------------- pooling init + head ----------------

__global__ void init_g(unsigned* __restrict__ gU) {
  int i = blockIdx.x * blockDim.x + threadIdx.x;
  if (i < N_GRAPHS * D) gU[i] = 0x007FFFFFu;  // mapf(-inf)
}

__global__ void head_kernel(const unsigned* __restrict__ gU,
                            const float* __restrict__ fcW1, const float* __restrict__ fcb1,
                            const float* __restrict__ fcW2, const float* __restrict__ fcb2,
                            float* __restrict__ out) {
  __shared__ float gbuf[64];
  __shared__ float hid[64];
  __shared__ float logit[N_CLASSES];
  __shared__ float red[2];
  const int gi = blockIdx.x;
  const int t = threadIdx.x;

  gbuf[t] = unmapf(gU[gi * D + t]);
  __syncthreads();

  float a = fcb1[t];
#pragma unroll
  for (int k = 0; k < 64; ++k) a = fmaf(gbuf[k], fcW1[k * 64 + t], a);
  hid[t] = fmaxf(a, 0.0f);
  __syncthreads();

  if (t < N_CLASSES) {
    float l = fcb2[t];
#pragma unroll
    for (int k = 0; k < 64; ++k) l = fmaf(hid[k], fcW2[k * N_CLASSES + t], l);
    logit[t] = l;
  }
  __syncthreads();

  if (t == 0) {
    float mx = logit[0];
    for (int i = 1; i < N_CLASSES; ++i) mx = fmaxf(mx, logit[i]);
    float s = 0.0f;
    for (int i = 0; i < N_CLASSES; ++i) s += expf(logit[i] - mx);
    red[0] = mx;
    red[1] = logf(s);
  }
  __syncthreads();

  if (t < N_CLASSES) out[gi * N_CLASSES + t] = logit[t] - red[0] - red[1];
}

// ---------------- launch ----------------

extern "C" void kernel_launch(void* const* d_in, const int* in_sizes, int n_in,
                              void* d_out, int out_size, void* d_ws, size_t ws_size,
                              hipStream_t stream) {
  const float* x      = (const float*)d_in[0];
  const float* convW1 = (const float*)d_in[1];
  const float* convb1 = (const float*)d_in[2];
  const float* convW2 = (const float*)d_in[3];
  const float* convb2 = (const float*)d_in[4];
  const float* fcW1   = (const float*)d_in[5];
  const float* fcb1   = (const float*)d_in[6];
  const float* fcW2   = (const float*)d_in[7];
  const float* fcb2   = (const float*)d_in[8];
  const int*   edge   = (const int*)d_in[9];
  const int*   batch  = (const int*)d_in[10];
  float* out = (float*)d_out;

  const int* src = edge;
  const int* dst = edge + N_EDGES;

  // workspace layout (~23 MB)
  unsigned* xb  = (unsigned*)d_ws;                  // 6.4 MB bf16 h
  unsigned* hbA = xb + (size_t)N_NODES * 32;        // 6.4 MB bf16 (agg out)
  unsigned* hbB = hbA + (size_t)N_NODES * 32;       // 6.4 MB bf16 (mlp out)
  unsigned* gU  = hbB + (size_t)N_NODES * 32;       // 131 KB
  int* rs  = (int*)(gU + N_GRAPHS * D);             // 200 KB
  int* csr = rs + N_NODES + 1;                      // 3.2 MB
  ushort* wf = (ushort*)(csr + N_EDGES);            // 96 KB
  // deg/cur/bsum overlap hbB (dead before hbB is first written by mlp #1)
  int* deg  = (int*)hbB;
  int* cur  = deg + N_NODES;
  int* bsum = cur + N_NODES;

  // ---- prep: x->bf16, W fragments, pool init ----
  to_bf16<<<(N_NODES * 16) / 256, 256, 0, stream>>>(x, xb);
  wprep<<<6, 512, 0, stream>>>(convW1, convW2, wf);
  init_g<<<(N_GRAPHS * D + 255) / 256, 256, 0, stream>>>(gU);

  // ---- CSR build (dst-indexed, XCD-partitioned writes) ----
  hipMemsetAsync(deg, 0, N_NODES * sizeof(int), stream);
  hist_part<<<2048, 256, 0, stream>>>(dst, deg);
  scan_blocks<<<NB_SCAN, SCAN_B, 0, stream>>>(deg, bsum);
  scan_mid<<<1, 256, 0, stream>>>(bsum);
  scan_final<<<NB_SCAN, SCAN_B, 0, stream>>>(deg, bsum, rs, cur);
  fill_part<<<2048, 256, 0, stream>>>(src, dst, cur, csr);

  // ---- 3 GIN layers: agg X->T (NT stores), mlp T->Y (NT stores) ----
  const int AGG_B = N_NODES / 8;      // 6250
  const int MLP_B = (NTILE + 3) / 4;  // 782
  agg_bf16<<<AGG_B, 256, 0, stream>>>(xb, csr, rs, hbA);
  mlp_bf16<0><<<MLP_B, 256, 0, stream>>>(hbA, hbB, wf, convb1, convb2, batch, gU);
  agg_bf16<<<AGG_B, 256, 0, stream>>>(hbB, csr, rs, hbA);
  mlp_bf16<0><<<MLP_B, 256, 0, stream>>>(hbA, xb, wf + 16384, convb1 + 64,
                                         convb2 + 64, batch, gU);
  agg_bf16<<<AGG_B, 256, 0, stream>>>(xb, csr, rs, hbA);
  mlp_bf16<1><<<MLP_B, 256, 0, stream>>>(hbA, nullptr, wf + 32768, convb1 + 128,
                                         convb2 + 128, batch, gU);

  // ---- FC head + log_softmax ----
  head_kernel<<<N_GRAPHS, 64, 0, stream>>>(gU, fcW1, fcb1, fcW2, fcb2, out);

  // ==== DIAGNOSTICS (tail; dead writes; deterministic) ====
  // abl_again: gather with REGULAR stores -> hbB becomes fresh-dirty
  abl_again<<<AGG_B, 256, 0, stream>>>(xb, csr, rs, hbB);
  // abl_fresh: mlp clone reading that fresh-dirty buffer -> the freshness probe
  abl_fresh<<<MLP_B, 256, 0, stream>>>(hbB, hbA, wf + 16384, convb1 + 64,
                                       convb2 + 64, batch, gU);
}

// Round 16
// 238.180 us; speedup vs baseline: 2.9908x; 1.0783x over previous
//
#include <hip/hip_runtime.h>
#include <math.h>

#define N_NODES 50000
#define N_EDGES 800000
#define D 64
#define N_GRAPHS 512
#define N_CLASSES 10
#define NTILE 3125     // 16-row tiles
#define NPART 6250     // nodes per XCD partition (50000/8)

#define SCAN_B 512
#define NB_SCAN ((N_NODES + SCAN_B - 1) / SCAN_B)  // 98

typedef __attribute__((ext_vector_type(8))) short bf16x8;
typedef __attribute__((ext_vector_type(4))) float f32x4;
typedef __attribute__((ext_vector_type(4))) unsigned uint4v;

#define MFMA16(a, b, c) __builtin_amdgcn_mfma_f32_16x16x32_bf16(a, b, c, 0, 0, 0)

// ---------------- helpers ----------------

__device__ __forceinline__ unsigned mapf(float f) {
  unsigned u = __float_as_uint(f);
  return (u & 0x80000000u) ? ~u : (u | 0x80000000u);
}
__device__ __forceinline__ float unmapf(unsigned u) {
  return __uint_as_float((u & 0x80000000u) ? (u & 0x7FFFFFFFu) : ~u);
}
__device__ __forceinline__ ushort bf16_rne(float f) {
  unsigned u = __float_as_uint(f);
  u += 0x7FFFu + ((u >> 16) & 1u);
  return (ushort)(u >> 16);
}
__device__ __forceinline__ float bf16_tof(ushort h) {
  return __uint_as_float(((unsigned)h) << 16);
}
__device__ __forceinline__ unsigned pack2(float a, float b) {
  return (unsigned)bf16_rne(a) | ((unsigned)bf16_rne(b) << 16);
}
__device__ __forceinline__ float2 unpack2(unsigned v) {
  return make_float2(__uint_as_float(v << 16), __uint_as_float(v & 0xFFFF0000u));
}

// ---------------- x -> bf16 ----------------

__global__ void to_bf16(const float* __restrict__ in, unsigned* __restrict__ out) {
  int i = blockIdx.x * 256 + threadIdx.x;
  float4 v = reinterpret_cast<const float4*>(in)[i];
  reinterpret_cast<uint2*>(out)[i] = make_uint2(pack2(v.x, v.y), pack2(v.z, v.w));
}

// ---------------- weight fragment prep (hi/lo split) ----------------
// wf (ushorts): per layer 16384: W1hi@0, W1lo@4096, W2hi@8192, W2lo@12288.
// within region: frag f (8), lane (64), v (8): off = f*512 + lane*8 + v
// value = W[k][n], k = (f&1)*32 + (lane>>4)*8 + v, n = (f>>1)*16 + (lane&15)
// NTS=1: non-temporal stores -> lines land CLEAN (no single-XCD dirty owner),
// so the 782 consumer blocks' staging reads can replicate into every L2.

template <int NTS>
__device__ __forceinline__ void wprep_body(const float* __restrict__ convW1,
                                           const float* __restrict__ convW2,
                                           ushort* __restrict__ wf, int bid, int t) {
  const int layer = bid >> 1, which = bid & 1;
  const float* W = (which ? convW2 : convW1) + layer * 4096;
  const int f = t >> 6, lane = t & 63;
  const int ct = f >> 1, ks = f & 1;
  const int n = ct * 16 + (lane & 15);
  const int k0 = ks * 32 + ((lane >> 4) << 3);
  ushort hi[8], lo[8];
#pragma unroll
  for (int v = 0; v < 8; ++v) {
    float w = W[(k0 + v) * 64 + n];
    ushort h = bf16_rne(w);
    hi[v] = h;
    lo[v] = bf16_rne(w - bf16_tof(h));
  }
  ushort* base = wf + layer * 16384 + which * 8192;
  if (NTS) {
    __builtin_nontemporal_store(*(uint4v*)hi, (uint4v*)(base + f * 512 + lane * 8));
    __builtin_nontemporal_store(*(uint4v*)lo, (uint4v*)(base + 4096 + f * 512 + lane * 8));
  } else {
    *(uint4*)(base + f * 512 + lane * 8) = *(uint4*)hi;
    *(uint4*)(base + 4096 + f * 512 + lane * 8) = *(uint4*)lo;
  }
}

__global__ void wprep(const float* __restrict__ convW1, const float* __restrict__ convW2,
                      ushort* __restrict__ wf) {
  wprep_body<1>(convW1, convW2, wf, blockIdx.x, threadIdx.x);
}

// diagnostic: regular stores (re-dirties wf in a few L2s)
__global__ void wprep_reg(const float* __restrict__ convW1, const float* __restrict__ convW2,
                          ushort* __restrict__ wf) {
  wprep_body<0>(convW1, convW2, wf, blockIdx.x, threadIdx.x);
}

// ---------------- CSR build (XCD-partitioned writes) ----------------

__global__ void hist_part(const int* __restrict__ dst, int* __restrict__ deg) {
  const int p = blockIdx.x & 7;
  const int lo = p * NPART, hi = lo + NPART;
  const int stride = (gridDim.x >> 3) * 256;
  for (int e = (blockIdx.x >> 3) * 256 + threadIdx.x; e < N_EDGES; e += stride) {
    int d = dst[e];
    if (d >= lo && d < hi) atomicAdd(&deg[d], 1);
  }
}

__global__ void scan_blocks(const int* __restrict__ deg, int* __restrict__ bsum) {
  __shared__ int sd[SCAN_B];
  int i = blockIdx.x * SCAN_B + threadIdx.x;
  sd[threadIdx.x] = (i < N_NODES) ? deg[i] : 0;
  __syncthreads();
  for (int off = SCAN_B / 2; off > 0; off >>= 1) {
    if (threadIdx.x < off) sd[threadIdx.x] += sd[threadIdx.x + off];
    __syncthreads();
  }
  if (threadIdx.x == 0) bsum[blockIdx.x] = sd[0];
}

__global__ void scan_mid(int* __restrict__ bsum) {
  __shared__ int s[256];
  int t = threadIdx.x;
  if (t < NB_SCAN) s[t] = bsum[t];
  __syncthreads();
  if (t == 0) {
    int run = 0;
    for (int i = 0; i < NB_SCAN; ++i) { int v = s[i]; s[i] = run; run += v; }
  }
  __syncthreads();
  if (t < NB_SCAN) bsum[t] = s[t];
}

__global__ void scan_final(const int* __restrict__ deg, const int* __restrict__ bsum,
                           int* __restrict__ rs, int* __restrict__ cur) {
  __shared__ int sd[SCAN_B];
  int i = blockIdx.x * SCAN_B + threadIdx.x;
  int v = (i < N_NODES) ? deg[i] : 0;
  sd[threadIdx.x] = v;
  __syncthreads();
  for (int off = 1; off < SCAN_B; off <<= 1) {
    int add = (threadIdx.x >= off) ? sd[threadIdx.x - off] : 0;
    __syncthreads();
    sd[threadIdx.x] += add;
    __syncthreads();
  }
  if (i < N_NODES) {
    int ex = bsum[blockIdx.x] + sd[threadIdx.x] - v;
    rs[i] = ex;
    cur[i] = ex;
  }
  if (i == 0) rs[N_NODES] = N_EDGES;
}

__global__ void fill_part(const int* __restrict__ src, const int* __restrict__ dst,
                          int* __restrict__ cur, int* __restrict__ csr) {
  const int p = blockIdx.x & 7;
  const int lo = p * NPART, hi = lo + NPART;
  const int stride = (gridDim.x >> 3) * 256;
  for (int e = (blockIdx.x >> 3) * 256 + threadIdx.x; e < N_EDGES; e += stride) {
    int d = dst[e];
    if (d >= lo && d < hi) {
      int pos = atomicAdd(&cur[d], 1);
      csr[pos] = src[e];
    }
  }
}

// ---------------- GIN aggregation ----------------

__global__ __launch_bounds__(256) void agg_bf16(
    const unsigned* __restrict__ hin, const int* __restrict__ csr,
    const int* __restrict__ rs, unsigned* __restrict__ hout) {
  const int t = threadIdx.x;
  const int hw = t >> 5, hl = t & 31;
  const int node = blockIdx.x * 8 + hw;
  float2 a = unpack2(hin[node * 32 + hl]);  // self term
  int e = rs[node];
  const int e1 = rs[node + 1];
  for (; e + 4 <= e1; e += 4) {
    int s0 = csr[e], s1 = csr[e + 1], s2 = csr[e + 2], s3 = csr[e + 3];
    float2 v0 = unpack2(hin[s0 * 32 + hl]);
    float2 v1 = unpack2(hin[s1 * 32 + hl]);
    float2 v2 = unpack2(hin[s2 * 32 + hl]);
    float2 v3 = unpack2(hin[s3 * 32 + hl]);
    a.x += v0.x + v1.x; a.y += v0.y + v1.y;
    a.x += v2.x + v3.x; a.y += v2.y + v3.y;
  }
  for (; e < e1; ++e) {
    float2 v = unpack2(hin[csr[e] * 32 + hl]);
    a.x += v.x; a.y += v.y;
  }
  hout[node * 32 + hl] = pack2(a.x, a.y);
}

// ---------------- MFMA MLP body ----------------
// A-frag: lane row=lane&15, k=(ks*32)+(lane>>4)*8+v. C/D: col=lane&15, row=(lane>>4)*4+j.

template <int FINAL>
__device__ __forceinline__ void mlp_body(
    const unsigned* __restrict__ Ain, unsigned* __restrict__ Aout,
    const ushort* __restrict__ wfL,
    const float* __restrict__ b1, const float* __restrict__ b2,
    const int* __restrict__ batch, unsigned* __restrict__ gU,
    ushort* Wl, ushort* tb, int bid, int t) {
  const int w = t >> 6, lane = t & 63;
  const int tile = bid * 4 + w;
  const bool act = (tile < NTILE);
  const int m = lane & 15, g = lane >> 4;
  ushort* tw = tb + w * (16 * 72);

  {
    const uint4* s = (const uint4*)wfL;
    uint4* d = (uint4*)Wl;
#pragma unroll
    for (int i = 0; i < 8; ++i) d[t + 256 * i] = s[t + 256 * i];
  }
  bf16x8 a0 = {}, a1 = {};
  if (act) {
    const ushort* Ar = (const ushort*)Ain + (size_t)(tile * 16 + m) * 64;
    a0 = *(const bf16x8*)(Ar + g * 8);
    a1 = *(const bf16x8*)(Ar + 32 + g * 8);
  }
  __syncthreads();

  if (act) {
    const char* wb = (const char*)Wl + lane * 16;
#define LDW(off) (*(const bf16x8*)(wb + (off)))
    f32x4 c0 = {0.f, 0.f, 0.f, 0.f}, c1 = c0, c2 = c0, c3 = c0;
#define G1(ct, cc)                                      \
    cc = MFMA16(a0, LDW((2 * ct + 0) * 1024), cc);      \
    cc = MFMA16(a1, LDW((2 * ct + 1) * 1024), cc);      \
    cc = MFMA16(a0, LDW(8192 + (2 * ct + 0) * 1024), cc); \
    cc = MFMA16(a1, LDW(8192 + (2 * ct + 1) * 1024), cc);
    G1(0, c0) G1(1, c1) G1(2, c2) G1(3, c3)
#undef G1

    {
      float bv0 = b1[m], bv1 = b1[16 + m], bv2 = b1[32 + m], bv3 = b1[48 + m];
#define WRT(cc, ct, bv)                                                    \
      tw[(g * 4 + 0) * 72 + ct * 16 + m] = bf16_rne(fmaxf(cc[0] + bv, 0.f)); \
      tw[(g * 4 + 1) * 72 + ct * 16 + m] = bf16_rne(fmaxf(cc[1] + bv, 0.f)); \
      tw[(g * 4 + 2) * 72 + ct * 16 + m] = bf16_rne(fmaxf(cc[2] + bv, 0.f)); \
      tw[(g * 4 + 3) * 72 + ct * 16 + m] = bf16_rne(fmaxf(cc[3] + bv, 0.f));
      WRT(c0, 0, bv0) WRT(c1, 1, bv1) WRT(c2, 2, bv2) WRT(c3, 3, bv3)
#undef WRT
    }
    bf16x8 h0 = *(const bf16x8*)(tw + m * 72 + g * 8);
    bf16x8 h1 = *(const bf16x8*)(tw + m * 72 + 32 + g * 8);

    c0 = (f32x4){0.f, 0.f, 0.f, 0.f}; c1 = c0; c2 = c0; c3 = c0;
#define G2(ct, cc)                                       \
    cc = MFMA16(h0, LDW(16384 + (2 * ct + 0) * 1024), cc); \
    cc = MFMA16(h1, LDW(16384 + (2 * ct + 1) * 1024), cc); \
    cc = MFMA16(h0, LDW(24576 + (2 * ct + 0) * 1024), cc); \
    cc = MFMA16(h1, LDW(24576 + (2 * ct + 1) * 1024), cc);
    G2(0, c0) G2(1, c1) G2(2, c2) G2(3, c3)
#undef G2
#undef LDW

    const float bv20 = b2[m], bv21 = b2[16 + m], bv22 = b2[32 + m], bv23 = b2[48 + m];
    if (FINAL) {
      int b40 = batch[tile * 16 + g * 4 + 0];
      int b41 = batch[tile * 16 + g * 4 + 1];
      int b42 = batch[tile * 16 + g * 4 + 2];
      int b43 = batch[tile * 16 + g * 4 + 3];
#define PM(cc, ct, bv)                                          \
      atomicMax(&gU[b40 * 64 + ct * 16 + m], mapf(cc[0] + bv)); \
      atomicMax(&gU[b41 * 64 + ct * 16 + m], mapf(cc[1] + bv)); \
      atomicMax(&gU[b42 * 64 + ct * 16 + m], mapf(cc[2] + bv)); \
      atomicMax(&gU[b43 * 64 + ct * 16 + m], mapf(cc[3] + bv));
      PM(c0, 0, bv20) PM(c1, 1, bv21) PM(c2, 2, bv22) PM(c3, 3, bv23)
#undef PM
    } else {
#define WRO(cc, ct, bv)                                        \
      tw[(g * 4 + 0) * 72 + ct * 16 + m] = bf16_rne(cc[0] + bv); \
      tw[(g * 4 + 1) * 72 + ct * 16 + m] = bf16_rne(cc[1] + bv); \
      tw[(g * 4 + 2) * 72 + ct * 16 + m] = bf16_rne(cc[2] + bv); \
      tw[(g * 4 + 3) * 72 + ct * 16 + m] = bf16_rne(cc[3] + bv);
      WRO(c0, 0, bv20) WRO(c1, 1, bv21) WRO(c2, 2, bv22) WRO(c3, 3, bv23)
#undef WRO
      const int r = lane >> 2, q = lane & 3;
      uint4 v0 = *(const uint4*)(tw + r * 72 + q * 16);
      uint4 v1 = *(const uint4*)(tw + r * 72 + q * 16 + 8);
      ushort* Ao = (ushort*)Aout + (size_t)tile * 1024;
      *(uint4*)(Ao + lane * 16) = v0;
      *(uint4*)(Ao + lane * 16 + 8) = v1;
    }
  }
}

template <int FINAL>
__global__ __launch_bounds__(256, 2) void mlp_bf16(
    const unsigned* __restrict__ Ain, unsigned* __restrict__ Aout,
    const ushort* __restrict__ wfL,
    const float* __restrict__ b1, const float* __restrict__ b2,
    const int* __restrict__ batch, unsigned* __restrict__ gU) {
  __shared__ ushort Wl[16384];
  __shared__ ushort tb[4 * 16 * 72];
  mlp_body<FINAL>(Ain, Aout, wfL, b1, b2, batch, gU, Wl, tb,
                  blockIdx.x, threadIdx.x);
}

// diagnostic: exact mlp clone (runs at tail AFTER wprep_reg re-dirties wf)
__global__ __launch_bounds__(256, 2) void abl_wdirty(
    const unsigned* __restrict__ Ain, unsigned* __restrict__ Aout,
    const ushort* __restrict__ wfL,
    const float* __restrict__ b1, const float* __restrict__ b2,
    const int* __restrict__ batch, unsigned* __restrict__ gU) {
  __shared__ ushort Wl[16384];
  __shared__ ushort tb[4 * 16 * 72];
  mlp_body<0>(Ain, Aout, wfL, b1, b2, batch, gU, Wl, tb,
              blockIdx.x, threadIdx.x);
}

// ---------------- pooling init + head ----------------

__global__ void init_g(unsigned* __restrict__ gU) {
  int i = blockIdx.x * blockDim.x + threadIdx.x;
  if (i < N_GRAPHS * D) gU[i] = 0x007FFFFFu;  // mapf(-inf)
}

__global__ void head_kernel(const unsigned* __restrict__ gU,
                            const float* __restrict__ fcW1, const float* __restrict__ fcb1,
                            const float* __restrict__ fcW2, const float* __restrict__ fcb2,
                            float* __restrict__ out) {
  __shared__ float gbuf[64];
  __shared__ float hid[64];
  __shared__ float logit[N_CLASSES];
  __shared__ float red[2];
  const int gi = blockIdx.x;
  const int t = threadIdx.x;

  gbuf[t] = unmapf(gU[gi * D + t]);
  __syncthreads();

  float a = fcb1[t];
#pragma unroll
  for (int k = 0; k < 64; ++k) a = fmaf(gbuf[k], fcW1[k * 64 + t], a);
  hid[t] = fmaxf(a, 0.0f);
  __syncthreads();

  if (t < N_CLASSES) {
    float l = fcb2[t];
#pragma unroll
    for (int k = 0; k < 64; ++k) l = fmaf(hid[k], fcW2[k * N_CLASSES + t], l);
    logit[t] = l;
  }
  __syncthreads();

  if (t == 0) {
    float mx = logit[0];
    for (int i = 1; i < N_CLASSES; ++i) mx = fmaxf(mx, logit[i]);
    float s = 0.0f;
    for (int i = 0; i < N_CLASSES; ++i) s += expf(logit[i] - mx);
    red[0] = mx;
    red[1] = logf(s);
  }
  __syncthreads();

  if (t < N_CLASSES) out[gi * N_CLASSES + t] = logit[t] - red[0] - red[1];
}

// ---------------- launch ----------------

extern "C" void kernel_launch(void* const* d_in, const int* in_sizes, int n_in,
                              void* d_out, int out_size, void* d_ws, size_t ws_size,
                              hipStream_t stream) {
  const float* x      = (const float*)d_in[0];
  const float* convW1 = (const float*)d_in[1];
  const float* convb1 = (const float*)d_in[2];
  const float* convW2 = (const float*)d_in[3];
  const float* convb2 = (const float*)d_in[4];
  const float* fcW1   = (const float*)d_in[5];
  const float* fcb1   = (const float*)d_in[6];
  const float* fcW2   = (const float*)d_in[7];
  const float* fcb2   = (const float*)d_in[8];
  const int*   edge   = (const int*)d_in[9];
  const int*   batch  = (const int*)d_in[10];
  float* out = (float*)d_out;

  const int* src = edge;
  const int* dst = edge + N_EDGES;

  // workspace layout (~23 MB)
  unsigned* xb  = (unsigned*)d_ws;                  // 6.4 MB bf16 h
  unsigned* hbA = xb + (size_t)N_NODES * 32;        // 6.4 MB bf16 (agg out)
  unsigned* hbB = hbA + (size_t)N_NODES * 32;       // 6.4 MB bf16 (mlp out)
  unsigned* gU  = hbB + (size_t)N_NODES * 32;       // 131 KB
  int* rs  = (int*)(gU + N_GRAPHS * D);             // 200 KB
  int* csr = rs + N_NODES + 1;                      // 3.2 MB
  ushort* wf = (ushort*)(csr + N_EDGES);            // 96 KB
  // deg/cur/bsum overlap hbB (dead before hbB is first written by mlp #1)
  int* deg  = (int*)hbB;
  int* cur  = deg + N_NODES;
  int* bsum = cur + N_NODES;

  // ---- prep: x->bf16, W fragments (NT stores -> clean lines), pool init ----
  to_bf16<<<(N_NODES * 16) / 256, 256, 0, stream>>>(x, xb);
  wprep<<<6, 512, 0, stream>>>(convW1, convW2, wf);
  init_g<<<(N_GRAPHS * D + 255) / 256, 256, 0, stream>>>(gU);

  // ---- CSR build (dst-indexed, XCD-partitioned writes) ----
  hipMemsetAsync(deg, 0, N_NODES * sizeof(int), stream);
  hist_part<<<2048, 256, 0, stream>>>(dst, deg);
  scan_blocks<<<NB_SCAN, SCAN_B, 0, stream>>>(deg, bsum);
  scan_mid<<<1, 256, 0, stream>>>(bsum);
  scan_final<<<NB_SCAN, SCAN_B, 0, stream>>>(deg, bsum, rs, cur);
  fill_part<<<2048, 256, 0, stream>>>(src, dst, cur, csr);

  // ---- 3 GIN layers ----
  const int AGG_B = N_NODES / 8;      // 6250
  const int MLP_B = (NTILE + 3) / 4;  // 782
  agg_bf16<<<AGG_B, 256, 0, stream>>>(xb, csr, rs, hbA);
  mlp_bf16<0><<<MLP_B, 256, 0, stream>>>(hbA, hbB, wf, convb1, convb2, batch, gU);
  agg_bf16<<<AGG_B, 256, 0, stream>>>(hbB, csr, rs, hbA);
  mlp_bf16<0><<<MLP_B, 256, 0, stream>>>(hbA, xb, wf + 16384, convb1 + 64,
                                         convb2 + 64, batch, gU);
  agg_bf16<<<AGG_B, 256, 0, stream>>>(xb, csr, rs, hbA);
  mlp_bf16<1><<<MLP_B, 256, 0, stream>>>(hbA, nullptr, wf + 32768, convb1 + 128,
                                         convb2 + 128, batch, gU);

  // ---- FC head + log_softmax ----
  head_kernel<<<N_GRAPHS, 64, 0, stream>>>(gU, fcW1, fcb1, fcW2, fcb2, out);

  // ==== DIAGNOSTIC A/B (tail; dead writes; deterministic) ====
  // Re-dirty wf with REGULAR stores, then run an exact mlp clone.
  // Theory predicts abl_wdirty ~45-50us (vs R10's warm-weight clone ~5us).
  wprep_reg<<<6, 512, 0, stream>>>(convW1, convW2, wf);
  abl_wdirty<<<MLP_B, 256, 0, stream>>>(xb, hbA, wf + 16384, convb1 + 64,
                                        convb2 + 64, batch, gU);
}